// Round 6
// baseline (148.765 us; speedup 1.0000x reference)
//
#include <hip/hip_runtime.h>

// CompositeLoss: boundary-weighted BCE + Dice over (32,1,512,512)
// pred: float32 uniform [0,1), target: int32 binary {0,1}
// out: [total, bce, dice] float32
//
// R6 = R4 compute (passed, absmax 0.0) + fused finalize: no second kernel.
// Per block: reduce -> fp32 atomicAdd into global acc -> threadfence ->
// ticket atomicAdd; ticket==NBLK-1 block reads coherent totals (atomicAdd+0)
// and writes the 3 outputs. acc+counter zeroed per call via hipMemsetAsync
// (graph-legal memset node).

#define BB 32
#define HH 512
#define WW 512
#define N_TOTAL (BB * HH * WW)
#define NBLK 2048                 // 4 waves/block, 1 wave = one 2-row strip

__global__ __launch_bounds__(256) void loss_main_kernel(
        const float* __restrict__ pred,
        const int* __restrict__ target,
        float* __restrict__ acc,          // acc[0..3]
        unsigned* __restrict__ counter,   // arrival ticket
        float* __restrict__ out) {
    const int wave = threadIdx.x >> 6;
    const int lane = threadIdx.x & 63;
    const int gw   = blockIdx.x * 4 + wave;   // strip id, 0..8191
    const int b    = gw >> 8;                 // 256 strips per image
    const int h0   = (gw & 255) << 1;         // center rows h0, h0+1
    const int w0   = lane << 3;               // 8 contiguous px per lane

    const size_t img = (size_t)b * (HH * WW);
    const int* tg   = target + img;
    const float* pg = pred + img;

    const int hm = (h0 > 0) ? h0 - 1 : 0;            // clamp top
    const int hp = (h0 + 2 < HH) ? h0 + 2 : HH - 1;  // clamp bottom

    // ---- 4 target rows x 8 cols, 2 pred rows x 8 cols (all coalesced) ----
    const int4 r0A = *(const int4*)(tg + (size_t)hm * WW + w0);
    const int4 r0B = *(const int4*)(tg + (size_t)hm * WW + w0 + 4);
    const int4 r1A = *(const int4*)(tg + (size_t)h0 * WW + w0);
    const int4 r1B = *(const int4*)(tg + (size_t)h0 * WW + w0 + 4);
    const int4 r2A = *(const int4*)(tg + (size_t)(h0 + 1) * WW + w0);
    const int4 r2B = *(const int4*)(tg + (size_t)(h0 + 1) * WW + w0 + 4);
    const int4 r3A = *(const int4*)(tg + (size_t)hp * WW + w0);
    const int4 r3B = *(const int4*)(tg + (size_t)hp * WW + w0 + 4);

    const float4 pT0 = *(const float4*)(pg + (size_t)h0 * WW + w0);
    const float4 pT1 = *(const float4*)(pg + (size_t)h0 * WW + w0 + 4);
    const float4 pB0 = *(const float4*)(pg + (size_t)(h0 + 1) * WW + w0);
    const float4 pB1 = *(const float4*)(pg + (size_t)(h0 + 1) * WW + w0 + 4);

    // ---- vertical or/and per column, both center rows (share middle pair) --
#define VC(i, u, c1, c2, d)                                          \
    const int so##i = (c1) | (c2), sa##i = (c1) & (c2);              \
    const int oT##i = so##i | (u), nT##i = sa##i & (u);              \
    const int oB##i = so##i | (d), nB##i = sa##i & (d);
    VC(0, r0A.x, r1A.x, r2A.x, r3A.x)
    VC(1, r0A.y, r1A.y, r2A.y, r3A.y)
    VC(2, r0A.z, r1A.z, r2A.z, r3A.z)
    VC(3, r0A.w, r1A.w, r2A.w, r3A.w)
    VC(4, r0B.x, r1B.x, r2B.x, r3B.x)
    VC(5, r0B.y, r1B.y, r2B.y, r3B.y)
    VC(6, r0B.z, r1B.z, r2B.z, r3B.z)
    VC(7, r0B.w, r1B.w, r2B.w, r3B.w)
#undef VC

    // ---- halo columns via shuffle (wave spans the whole row), per row ----
    int oTL = __shfl_up(oT7, 1),   nTL = __shfl_up(nT7, 1);
    int oTR = __shfl_down(oT0, 1), nTR = __shfl_down(nT0, 1);
    int oBL = __shfl_up(oB7, 1),   nBL = __shfl_up(nB7, 1);
    int oBR = __shfl_down(oB0, 1), nBR = __shfl_down(nB0, 1);
    if (lane == 0)  { oTL = oT0; nTL = nT0; oBL = oB0; nBL = nB0; }
    if (lane == 63) { oTR = oT7; nTR = nT7; oBR = oB7; nBR = nB7; }

    // ---- horizontal window -> boundary flags (verbatim R3, per row) ----
    const int eT0 = (oTL | oT0 | oT1) != (nTL & nT0 & nT1);
    const int eT1 = (oT0 | oT1 | oT2) != (nT0 & nT1 & nT2);
    const int eT2 = (oT1 | oT2 | oT3) != (nT1 & nT2 & nT3);
    const int eT3 = (oT2 | oT3 | oT4) != (nT2 & nT3 & nT4);
    const int eT4 = (oT3 | oT4 | oT5) != (nT3 & nT4 & nT5);
    const int eT5 = (oT4 | oT5 | oT6) != (nT4 & nT5 & nT6);
    const int eT6 = (oT5 | oT6 | oT7) != (nT5 & nT6 & nT7);
    const int eT7 = (oT6 | oT7 | oTR) != (nT6 & nT7 & nTR);
    const int eB0 = (oBL | oB0 | oB1) != (nBL & nB0 & nB1);
    const int eB1 = (oB0 | oB1 | oB2) != (nB0 & nB1 & nB2);
    const int eB2 = (oB1 | oB2 | oB3) != (nB1 & nB2 & nB3);
    const int eB3 = (oB2 | oB3 | oB4) != (nB2 & nB3 & nB4);
    const int eB4 = (oB3 | oB4 | oB5) != (nB3 & nB4 & nB5);
    const int eB5 = (oB4 | oB5 | oB6) != (nB4 & nB5 & nB6);
    const int eB6 = (oB5 | oB6 | oB7) != (nB5 & nB6 & nB7);
    const int eB7 = (oB6 | oB7 | oBR) != (nB6 & nB7 & nBR);

    float wbce = 0.f, inter = 0.f, sp = 0.f;
    int st_i = 0;

#define ACC(T, P, E)                                                   \
    {                                                                  \
        const float pc = fminf(fmaxf((P), 1e-7f), 1.0f - 1e-7f);       \
        const float x  = (T) ? pc : (1.0f - pc);                       \
        wbce += ((E) ? 3.0f : 1.0f) * (-__logf(x));                    \
        sp += (P);                                                     \
        if (T) inter += (P);                                           \
        st_i += (T);                                                   \
    }
    ACC(r1A.x, pT0.x, eT0); ACC(r1A.y, pT0.y, eT1);
    ACC(r1A.z, pT0.z, eT2); ACC(r1A.w, pT0.w, eT3);
    ACC(r1B.x, pT1.x, eT4); ACC(r1B.y, pT1.y, eT5);
    ACC(r1B.z, pT1.z, eT6); ACC(r1B.w, pT1.w, eT7);
    ACC(r2A.x, pB0.x, eB0); ACC(r2A.y, pB0.y, eB1);
    ACC(r2A.z, pB0.z, eB2); ACC(r2A.w, pB0.w, eB3);
    ACC(r2B.x, pB1.x, eB4); ACC(r2B.y, pB1.y, eB5);
    ACC(r2B.z, pB1.z, eB6); ACC(r2B.w, pB1.w, eB7);
#undef ACC

    // ---- wave reduction, then block reduction ----
    float st = (float)st_i;
    #pragma unroll
    for (int off = 32; off > 0; off >>= 1) {
        wbce  += __shfl_down(wbce,  off);
        inter += __shfl_down(inter, off);
        sp    += __shfl_down(sp,    off);
        st    += __shfl_down(st,    off);
    }

    __shared__ float smem[4][4];
    if ((threadIdx.x & 63) == 0) {
        smem[wave][0] = wbce; smem[wave][1] = inter;
        smem[wave][2] = sp;   smem[wave][3] = st;
    }
    __syncthreads();
    if (threadIdx.x == 0) {
        float s0 = 0, s1 = 0, s2 = 0, s3 = 0;
        #pragma unroll
        for (int wv = 0; wv < 4; ++wv) {
            s0 += smem[wv][0]; s1 += smem[wv][1];
            s2 += smem[wv][2]; s3 += smem[wv][3];
        }
        atomicAdd(&acc[0], s0);
        atomicAdd(&acc[1], s1);
        atomicAdd(&acc[2], s2);
        atomicAdd(&acc[3], s3);
        __threadfence();
        const unsigned t = atomicAdd(counter, 1u);
        if (t == NBLK - 1) {
            // all blocks' acc-adds are globally performed (fence-ordered
            // before their tickets). Coherent read via RMW at coherence pt.
            const double g0 = (double)atomicAdd(&acc[0], 0.0f);
            const double g1 = (double)atomicAdd(&acc[1], 0.0f);
            const double g2 = (double)atomicAdd(&acc[2], 0.0f);
            const double g3 = (double)atomicAdd(&acc[3], 0.0f);
            const double bce = g0 / (double)N_TOTAL;
            const double dice_coef = (2.0 * g1 + 1e-6) / (g2 + g3 + 1e-6);
            const double dice = 1.0 - dice_coef;
            const double total = 0.5 * bce + 0.5 * dice;
            out[0] = (float)total;
            out[1] = (float)bce;
            out[2] = (float)dice;
        }
    }
}

extern "C" void kernel_launch(void* const* d_in, const int* in_sizes, int n_in,
                              void* d_out, int out_size, void* d_ws, size_t ws_size,
                              hipStream_t stream) {
    const float* pred  = (const float*)d_in[0];
    const int* target  = (const int*)d_in[1];
    float* out = (float*)d_out;
    float* acc = (float*)d_ws;                          // 4 floats
    unsigned* counter = (unsigned*)((char*)d_ws + 16);  // 1 uint

    hipMemsetAsync(d_ws, 0, 32, stream);  // zero acc + counter (memset node)
    loss_main_kernel<<<NBLK, 256, 0, stream>>>(pred, target, acc, counter, out);
}

// Round 7
// 23.451 us; speedup vs baseline: 6.3436x; 6.3436x over previous
//
#include <hip/hip_runtime.h>

// CompositeLoss: boundary-weighted BCE + Dice over (32,1,512,512)
// pred: float32 uniform [0,1), target: int32 binary {0,1}
// out: [total, bce, dice] float32
//
// R7 = R4 structure (passed, absmax 0.0) with ONE change: each wave handles a
// 4-row vertical strip. 6 target rows + 4 pred rows loaded fully up front
// (20 coalesced 16B loads -> MLP 20/wave), then the R3-proven per-row
// boundary/ACC body applied verbatim per center row via DOROW macro.
// Target redundancy 2x -> 1.5x; waves 8192 -> 4096. Two-kernel reduce
// (R6 proved same-address atomics cost ~140us; never again).

#define BB 32
#define HH 512
#define WW 512
#define N_TOTAL (BB * HH * WW)
#define NBLK 1024                 // 4 waves/block, 1 wave = one 4-row strip

__global__ __launch_bounds__(256) void loss_main_kernel(
        const float* __restrict__ pred,
        const int* __restrict__ target,
        float4* __restrict__ partials) {
    const int wave = threadIdx.x >> 6;
    const int lane = threadIdx.x & 63;
    const int gw   = blockIdx.x * 4 + wave;   // strip id, 0..4095
    const int b    = gw >> 7;                 // 128 strips per image
    const int h0   = (gw & 127) << 2;         // center rows h0..h0+3
    const int w0   = lane << 3;               // 8 contiguous px per lane

    const int img = b * (HH * WW);            // fits int32 (max ~8.4M elems)
    const int* tg   = target + img;
    const float* pg = pred + img;

    const int hm = (h0 > 0) ? h0 - 1 : 0;            // clamp top
    const int hp = (h0 + 4 < HH) ? h0 + 4 : HH - 1;  // clamp bottom

    // ---- ALL loads up front: 6 target rows + 4 pred rows (20 x 16B) ----
    const int4 r0A = *(const int4*)(tg + hm * WW + w0);
    const int4 r0B = *(const int4*)(tg + hm * WW + w0 + 4);
    const int4 r1A = *(const int4*)(tg + h0 * WW + w0);
    const int4 r1B = *(const int4*)(tg + h0 * WW + w0 + 4);
    const int4 r2A = *(const int4*)(tg + (h0 + 1) * WW + w0);
    const int4 r2B = *(const int4*)(tg + (h0 + 1) * WW + w0 + 4);
    const int4 r3A = *(const int4*)(tg + (h0 + 2) * WW + w0);
    const int4 r3B = *(const int4*)(tg + (h0 + 2) * WW + w0 + 4);
    const int4 r4A = *(const int4*)(tg + (h0 + 3) * WW + w0);
    const int4 r4B = *(const int4*)(tg + (h0 + 3) * WW + w0 + 4);
    const int4 r5A = *(const int4*)(tg + hp * WW + w0);
    const int4 r5B = *(const int4*)(tg + hp * WW + w0 + 4);

    const float4 q0a = *(const float4*)(pg + h0 * WW + w0);
    const float4 q0b = *(const float4*)(pg + h0 * WW + w0 + 4);
    const float4 q1a = *(const float4*)(pg + (h0 + 1) * WW + w0);
    const float4 q1b = *(const float4*)(pg + (h0 + 1) * WW + w0 + 4);
    const float4 q2a = *(const float4*)(pg + (h0 + 2) * WW + w0);
    const float4 q2b = *(const float4*)(pg + (h0 + 2) * WW + w0 + 4);
    const float4 q3a = *(const float4*)(pg + (h0 + 3) * WW + w0);
    const float4 q3b = *(const float4*)(pg + (h0 + 3) * WW + w0 + 4);

    float wbce = 0.f, inter = 0.f, sp = 0.f;
    int st_i = 0;

#define ACC(T, P, E)                                                   \
    {                                                                  \
        const float pc = fminf(fmaxf((P), 1e-7f), 1.0f - 1e-7f);       \
        const float x  = (T) ? pc : (1.0f - pc);                       \
        wbce += ((E) ? 3.0f : 1.0f) * (-__logf(x));                    \
        sp += (P);                                                     \
        if (T) inter += (P);                                           \
        st_i += (T);                                                   \
    }

    // R3-proven per-row body, verbatim: rows (u, c, d), pred (P0, P1)
#define DOROW(uA, uB, cA, cB, dA, dB, P0, P1)                               \
    {                                                                       \
        const int o0 = uA.x | cA.x | dA.x,  n0 = uA.x & cA.x & dA.x;        \
        const int o1 = uA.y | cA.y | dA.y,  n1 = uA.y & cA.y & dA.y;        \
        const int o2 = uA.z | cA.z | dA.z,  n2 = uA.z & cA.z & dA.z;        \
        const int o3 = uA.w | cA.w | dA.w,  n3 = uA.w & cA.w & dA.w;        \
        const int o4 = uB.x | cB.x | dB.x,  n4 = uB.x & cB.x & dB.x;        \
        const int o5 = uB.y | cB.y | dB.y,  n5 = uB.y & cB.y & dB.y;        \
        const int o6 = uB.z | cB.z | dB.z,  n6 = uB.z & cB.z & dB.z;        \
        const int o7 = uB.w | cB.w | dB.w,  n7 = uB.w & cB.w & dB.w;        \
        int oL = __shfl_up(o7, 1),   nL = __shfl_up(n7, 1);                 \
        int oR = __shfl_down(o0, 1), nR = __shfl_down(n0, 1);               \
        if (lane == 0)  { oL = o0; nL = n0; }                               \
        if (lane == 63) { oR = o7; nR = n7; }                               \
        const int e0 = (oL | o0 | o1) != (nL & n0 & n1);                    \
        const int e1 = (o0 | o1 | o2) != (n0 & n1 & n2);                    \
        const int e2 = (o1 | o2 | o3) != (n1 & n2 & n3);                    \
        const int e3 = (o2 | o3 | o4) != (n2 & n3 & n4);                    \
        const int e4 = (o3 | o4 | o5) != (n3 & n4 & n5);                    \
        const int e5 = (o4 | o5 | o6) != (n4 & n5 & n6);                    \
        const int e6 = (o5 | o6 | o7) != (n5 & n6 & n7);                    \
        const int e7 = (o6 | o7 | oR) != (n6 & n7 & nR);                    \
        ACC(cA.x, P0.x, e0); ACC(cA.y, P0.y, e1);                           \
        ACC(cA.z, P0.z, e2); ACC(cA.w, P0.w, e3);                           \
        ACC(cB.x, P1.x, e4); ACC(cB.y, P1.y, e5);                           \
        ACC(cB.z, P1.z, e6); ACC(cB.w, P1.w, e7);                           \
    }

    DOROW(r0A, r0B, r1A, r1B, r2A, r2B, q0a, q0b)   // center row h0
    DOROW(r1A, r1B, r2A, r2B, r3A, r3B, q1a, q1b)   // center row h0+1
    DOROW(r2A, r2B, r3A, r3B, r4A, r4B, q2a, q2b)   // center row h0+2
    DOROW(r3A, r3B, r4A, r4B, r5A, r5B, q3a, q3b)   // center row h0+3
#undef DOROW
#undef ACC

    // ---- wave reduction, then one float4 partial per block ----
    float st = (float)st_i;
    #pragma unroll
    for (int off = 32; off > 0; off >>= 1) {
        wbce  += __shfl_down(wbce,  off);
        inter += __shfl_down(inter, off);
        sp    += __shfl_down(sp,    off);
        st    += __shfl_down(st,    off);
    }

    __shared__ float smem[4][4];
    if ((threadIdx.x & 63) == 0) {
        smem[wave][0] = wbce; smem[wave][1] = inter;
        smem[wave][2] = sp;   smem[wave][3] = st;
    }
    __syncthreads();
    if (threadIdx.x == 0) {
        float s0 = 0, s1 = 0, s2 = 0, s3 = 0;
        #pragma unroll
        for (int wv = 0; wv < 4; ++wv) {
            s0 += smem[wv][0]; s1 += smem[wv][1];
            s2 += smem[wv][2]; s3 += smem[wv][3];
        }
        partials[blockIdx.x] = make_float4(s0, s1, s2, s3);
    }
}

__global__ __launch_bounds__(1024) void finalize_kernel(
        const float4* __restrict__ partials, float* __restrict__ out) {
    const float4 p = partials[threadIdx.x];   // NBLK == 1024
    double a0 = p.x, a1 = p.y, a2 = p.z, a3 = p.w;
    #pragma unroll
    for (int off = 32; off > 0; off >>= 1) {
        a0 += __shfl_down(a0, off);
        a1 += __shfl_down(a1, off);
        a2 += __shfl_down(a2, off);
        a3 += __shfl_down(a3, off);
    }
    __shared__ double smem[16][4];
    const int wave = threadIdx.x >> 6;
    if ((threadIdx.x & 63) == 0) {
        smem[wave][0] = a0; smem[wave][1] = a1;
        smem[wave][2] = a2; smem[wave][3] = a3;
    }
    __syncthreads();
    if (threadIdx.x == 0) {
        double s0 = 0, s1 = 0, s2 = 0, s3 = 0;
        #pragma unroll
        for (int wv = 0; wv < 16; ++wv) {
            s0 += smem[wv][0]; s1 += smem[wv][1];
            s2 += smem[wv][2]; s3 += smem[wv][3];
        }
        const double bce = s0 / (double)N_TOTAL;
        const double dice_coef = (2.0 * s1 + 1e-6) / (s2 + s3 + 1e-6);
        const double dice = 1.0 - dice_coef;
        const double total = 0.5 * bce + 0.5 * dice;
        out[0] = (float)total;
        out[1] = (float)bce;
        out[2] = (float)dice;
    }
}

extern "C" void kernel_launch(void* const* d_in, const int* in_sizes, int n_in,
                              void* d_out, int out_size, void* d_ws, size_t ws_size,
                              hipStream_t stream) {
    const float* pred  = (const float*)d_in[0];
    const int* target  = (const int*)d_in[1];
    float* out = (float*)d_out;
    float4* partials = (float4*)d_ws;   // NBLK float4 = 16 KB

    loss_main_kernel<<<NBLK, 256, 0, stream>>>(pred, target, partials);
    finalize_kernel<<<1, 1024, 0, stream>>>(partials, out);
}